// Round 14
// baseline (57.760 us; speedup 1.0000x reference)
//
#include <hip/hip_runtime.h>
#include <hip/hip_bf16.h>

#define DM 2048
#define BB 64
#define SS 32
#define CC 8
#define NBA 512  // blocks in fused kernel A

typedef __attribute__((ext_vector_type(8))) short short8;
typedef __attribute__((ext_vector_type(4))) short short4v;
typedef __attribute__((ext_vector_type(4))) float f32x4;

static __device__ __forceinline__ short f2bf(float f) {
  union { __hip_bfloat16 h; short s; } u;
  u.h = __float2bfloat16(f);
  return u.s;
}

// Kernel A: phase0 (u16 = bf16(sum_c controls)) + lean grid barrier +
// r11-proven gemm1 body: v16[b][e] = bf16(sum_k u[b][k]Wv[e][k] + 8bv[e]).
// Barrier design (r9 fix): release-RMW arrive; RELAXED RMW poll (coherence
// point read, NO per-poll cache invalidate) + s_sleep; ONE acquire at exit.
// All 512 blocks co-resident (67KB LDS -> 2/CU; r9 demonstrated co-sched).
__global__ __launch_bounds__(256, 2) void fused_u_gemm1(
    const float* __restrict__ controls, const float* __restrict__ w,
    const float* __restrict__ bias, short* __restrict__ u16,
    short* __restrict__ vout, int* __restrict__ bar) {
  __shared__ float lwW[4][2][16 * 128];  // 64 KB
  __shared__ f32x4 red[3][64];           // 3 KB

  const int t   = threadIdx.x;
  const int bid = blockIdx.x;

  // ---- phase 0: this block's 1/512 slice of u16 (64 short4v units)
  if (t < 64) {
    const int idx = bid * 64 + t;  // 32768 units
    const int b = idx >> 9;
    const int k = (idx & 511) * 4;
    float4 s = make_float4(0.f, 0.f, 0.f, 0.f);
#pragma unroll
    for (int c = 0; c < CC; ++c) {
      const float4 v = *reinterpret_cast<const float4*>(
          controls + ((size_t)c * BB + b) * DM + k);
      s.x += v.x; s.y += v.y; s.z += v.z; s.w += v.w;
    }
    short4v o = {f2bf(s.x), f2bf(s.y), f2bf(s.z), f2bf(s.w)};
    *reinterpret_cast<short4v*>(u16 + (size_t)b * DM + k) = o;
  }

  // ---- lean grid barrier
  __syncthreads();
  if (t == 0) {
    __hip_atomic_fetch_add(bar, 1, __ATOMIC_RELEASE, __HIP_MEMORY_SCOPE_AGENT);
    while (__hip_atomic_fetch_add(bar, 0, __ATOMIC_RELAXED,
                                  __HIP_MEMORY_SCOPE_AGENT) < NBA)
      __builtin_amdgcn_s_sleep(10);
    (void)__hip_atomic_load(bar, __ATOMIC_ACQUIRE, __HIP_MEMORY_SCOPE_AGENT);
  }
  __syncthreads();

  // ---- gemm1 (r11-proven): tile 16e x 16b, 4 waves = 4 k-quarters,
  // chunks 128k dbuf, counted vmcnt(12).
  const int lane = t & 63;
  const int wv   = t >> 6;
  const int e0   = (bid & 127) * 16;
  const int b0   = (bid >> 7) * 16;
  const int kq   = wv * 512;

  const int wrl = lane >> 5, wg = lane & 31;
  const int r = lane & 15, ksub = lane >> 4;
  const int q = r & 7;

  const short* abase = u16 + (size_t)(b0 + r) * DM + kq + ksub * 8;
  short8 areg[2][4];
  f32x4 acc = {0.f, 0.f, 0.f, 0.f};

#define ISSUE_W(c, bsel)                                                      \
  {                                                                           \
    const int ck = kq + (c) * 128;                                            \
    float* wd = &lwW[wv][bsel][0];                                            \
    _Pragma("unroll") for (int i = 0; i < 8; ++i) {                           \
      const int row = 2 * i + wrl;                                            \
      const float* src =                                                      \
          w + (size_t)(e0 + row) * DM + ck + ((wg ^ (row & 7)) << 2);         \
      __builtin_amdgcn_global_load_lds(                                       \
          (const __attribute__((address_space(1))) void*)src,                 \
          (__attribute__((address_space(3))) void*)(wd + i * 256), 16, 0, 0); \
    }                                                                         \
  }
#define LOAD_A(c, bsel)                                                       \
  {                                                                           \
    _Pragma("unroll") for (int s = 0; s < 4; ++s) areg[bsel][s] =             \
        *reinterpret_cast<const short8*>(abase + (c) * 128 + s * 32);         \
  }

  ISSUE_W(0, 0)
  LOAD_A(0, 0)

#pragma unroll
  for (int c = 0; c < 4; ++c) {
    if (c < 3) {
      ISSUE_W(c + 1, (c + 1) & 1)
      LOAD_A(c + 1, (c + 1) & 1)
      asm volatile("s_waitcnt vmcnt(12)" ::: "memory");
    } else {
      asm volatile("s_waitcnt vmcnt(0)" ::: "memory");
    }
    __builtin_amdgcn_sched_barrier(0);

    const float* wb = &lwW[wv][c & 1][0];
#pragma unroll
    for (int s = 0; s < 4; ++s) {
      const int gl = s * 8 + ksub * 2;
      const float4 lo =
          *reinterpret_cast<const float4*>(wb + r * 128 + ((gl ^ q) << 2));
      const float4 hi = *reinterpret_cast<const float4*>(
          wb + r * 128 + (((gl + 1) ^ q) << 2));
      short8 bf;
      bf[0] = f2bf(lo.x); bf[1] = f2bf(lo.y);
      bf[2] = f2bf(lo.z); bf[3] = f2bf(lo.w);
      bf[4] = f2bf(hi.x); bf[5] = f2bf(hi.y);
      bf[6] = f2bf(hi.z); bf[7] = f2bf(hi.w);
      acc = __builtin_amdgcn_mfma_f32_16x16x32_bf16(areg[c & 1][s], bf, acc,
                                                    0, 0, 0);
    }
  }
#undef ISSUE_W
#undef LOAD_A

  if (wv != 0) red[wv - 1][lane] = acc;
  __syncthreads();
  if (wv == 0) {
#pragma unroll
    for (int i = 0; i < 3; ++i) acc += red[i][lane];
    const float be = 8.f * bias[e0 + r];
#pragma unroll
    for (int j = 0; j < 4; ++j)
      vout[(size_t)(b0 + ksub * 4 + j) * DM + e0 + r] = f2bf(acc[j] + be);
  }
}

// Kernel B: out[b][s][e] = seq[b][s][e] + (sum_k v[b][k]Wo[e][k] + 8bo[e])
// r13 structure + seq loads SPREAD across the 8 chunks (1/iter): constant
// vmcnt(8) = 1 old seq + 4 W + 2 A + 1 new seq in flight; last chunk
// vmcnt(1) (its seq may stay); epilogue vmcnt(0).
__global__ __launch_bounds__(512, 2) void gemm_out(
    const short* __restrict__ abf, const float* __restrict__ w,
    const float* __restrict__ bias, const float* __restrict__ seq,
    float* __restrict__ out) {
  __shared__ float lwW[8][2][16 * 64];  // 64 KB
  __shared__ f32x4 red[2][3][64];       // 6 KB
  __shared__ float ptt[16][32];         // 2 KB

  const int t    = threadIdx.x;
  const int lane = t & 63;
  const int wv   = t >> 6;
  const int eh   = wv & 1;
  const int kqi  = wv >> 1;
  const int e0   = (blockIdx.x & 63) * 32;
  const int b0   = (blockIdx.x >> 6) * 16;
  const int ew   = e0 + eh * 16;
  const int kq   = kqi * 512;

  const int rl4 = lane >> 4, g = lane & 15;
  const int r = lane & 15, ksub = lane >> 4;

  const short* abase = abf + (size_t)(b0 + r) * DM + kq + ksub * 8;
  short8 areg[2][2];
  f32x4 acc = {0.f, 0.f, 0.f, 0.f};

  const int bl = t >> 5, rem = t & 31;
  const int ef4 = (rem & 7) * 4, sl = rem >> 3;
  float4 sreg[8];

#define ISSUE_W2(c, bsel)                                                     \
  {                                                                           \
    const int ck = kq + (c) * 64;                                             \
    float* wd = &lwW[wv][bsel][0];                                            \
    _Pragma("unroll") for (int i = 0; i < 4; ++i) {                           \
      const int row = 4 * i + rl4;                                            \
      const float* src =                                                      \
          w + (size_t)(ew + row) * DM + ck + ((g ^ row) << 2);                \
      __builtin_amdgcn_global_load_lds(                                       \
          (const __attribute__((address_space(1))) void*)src,                 \
          (__attribute__((address_space(3))) void*)(wd + i * 256), 16, 0, 0); \
    }                                                                         \
  }
#define LOAD_A2(c, bsel)                                                      \
  {                                                                           \
    areg[bsel][0] = *reinterpret_cast<const short8*>(abase + (c) * 64);       \
    areg[bsel][1] = *reinterpret_cast<const short8*>(abase + (c) * 64 + 32);  \
  }
#define LOAD_SEQ(i)                                                           \
  {                                                                           \
    const size_t off =                                                        \
        ((size_t)(b0 + bl) * SS + (sl + 4 * (i))) * DM + e0 + ef4;            \
    sreg[i] = *reinterpret_cast<const float4*>(seq + off);                    \
  }

  ISSUE_W2(0, 0)
  LOAD_A2(0, 0)
  LOAD_SEQ(0)

#pragma unroll
  for (int c = 0; c < 8; ++c) {
    if (c < 7) {
      ISSUE_W2(c + 1, (c + 1) & 1)
      LOAD_A2(c + 1, (c + 1) & 1)
      LOAD_SEQ(c + 1)
      asm volatile("s_waitcnt vmcnt(8)" ::: "memory");
    } else {
      asm volatile("s_waitcnt vmcnt(1)" ::: "memory");
    }
    __builtin_amdgcn_sched_barrier(0);

    const float* wb = &lwW[wv][c & 1][0];
#pragma unroll
    for (int s = 0; s < 2; ++s) {
      const int gl = s * 8 + ksub * 2;
      const float4 lo =
          *reinterpret_cast<const float4*>(wb + r * 64 + ((gl ^ r) << 2));
      const float4 hi = *reinterpret_cast<const float4*>(
          wb + r * 64 + (((gl + 1) ^ r) << 2));
      short8 bf;
      bf[0] = f2bf(lo.x); bf[1] = f2bf(lo.y);
      bf[2] = f2bf(lo.z); bf[3] = f2bf(lo.w);
      bf[4] = f2bf(hi.x); bf[5] = f2bf(hi.y);
      bf[6] = f2bf(hi.z); bf[7] = f2bf(hi.w);
      acc = __builtin_amdgcn_mfma_f32_16x16x32_bf16(areg[c & 1][s], bf, acc,
                                                    0, 0, 0);
    }
  }
#undef ISSUE_W2
#undef LOAD_A2
#undef LOAD_SEQ

  if (kqi != 0) red[eh][kqi - 1][lane] = acc;
  __syncthreads();
  if (kqi == 0) {
#pragma unroll
    for (int i = 0; i < 3; ++i) acc += red[eh][i][lane];
    const float be = 8.f * bias[ew + r];
#pragma unroll
    for (int j = 0; j < 4; ++j) ptt[ksub * 4 + j][eh * 16 + r] = acc[j] + be;
  }
  __syncthreads();

  const float4 pv = *reinterpret_cast<const float4*>(&ptt[bl][ef4]);
  asm volatile("s_waitcnt vmcnt(0)" ::: "memory");
#pragma unroll
  for (int i = 0; i < 8; ++i) {
    const size_t off = ((size_t)(b0 + bl) * SS + (sl + 4 * i)) * DM + e0 + ef4;
    *reinterpret_cast<float4*>(out + off) =
        make_float4(sreg[i].x + pv.x, sreg[i].y + pv.y, sreg[i].z + pv.z,
                    sreg[i].w + pv.w);
  }
}

extern "C" void kernel_launch(void* const* d_in, const int* in_sizes, int n_in,
                              void* d_out, int out_size, void* d_ws,
                              size_t ws_size, hipStream_t stream) {
  const float* seq      = (const float*)d_in[0];
  const float* controls = (const float*)d_in[1];
  // d_in[2..5] = Wq, bq, Wk, bk — mathematically unused (softmax over size-1 axis == 1)
  const float* Wv = (const float*)d_in[6];
  const float* bv = (const float*)d_in[7];
  const float* Wo = (const float*)d_in[8];
  const float* bo = (const float*)d_in[9];
  float* out = (float*)d_out;

  char* ws = (char*)d_ws;
  int*   bar = (int*)(ws);                     // 4 KB, zeroed per call
  short* u16 = (short*)(ws + (4ull << 10));    // 256 KB bf16 [64][2048]
  short* v16 = (short*)(ws + (512ull << 10));  // 256 KB bf16 [64][2048]

  hipMemsetAsync(bar, 0, 4096, stream);
  fused_u_gemm1<<<NBA, 256, 0, stream>>>(controls, Wv, bv, u16, v16, bar);
  gemm_out<<<256, 512, 0, stream>>>(v16, Wo, bo, seq, out);
}

// Round 16
// 29.801 us; speedup vs baseline: 1.9382x; 1.9382x over previous
//
#include <hip/hip_runtime.h>
#include <hip/hip_bf16.h>

#define DM 2048
#define BB 64
#define SS 32
#define CC 8

typedef __attribute__((ext_vector_type(8))) short short8;
typedef __attribute__((ext_vector_type(4))) short short4v;
typedef __attribute__((ext_vector_type(4))) float f32x4;

static __device__ __forceinline__ short f2bf(float f) {
  union { __hip_bfloat16 h; short s; } u;
  u.h = __float2bfloat16(f);
  return u.s;
}

// K1: u16[b][k] = bf16(sum_c controls[c][b][k]).  grid 256 x 128
__global__ void k1_sum_bf16(const float* __restrict__ controls,
                            short* __restrict__ u16) {
  const int idx = blockIdx.x * 128 + threadIdx.x;  // 32768
  const int b = idx >> 9;
  const int k = (idx & 511) * 4;
  float4 s = make_float4(0.f, 0.f, 0.f, 0.f);
#pragma unroll
  for (int c = 0; c < CC; ++c) {
    const float4 v = *reinterpret_cast<const float4*>(
        controls + ((size_t)c * BB + b) * DM + k);
    s.x += v.x; s.y += v.y; s.z += v.z; s.w += v.w;
  }
  short4v o = {f2bf(s.x), f2bf(s.y), f2bf(s.z), f2bf(s.w)};
  *reinterpret_cast<short4v*>(u16 + (size_t)b * DM + k) = o;
}

// GEMM1 (r11-proven, verbatim): v16[b][e] = bf16(sum_k u[b][k]Wv[e][k]+8bv[e])
// Tile 16e x 16b; 4 waves = 4 k-quarters (512k); chunks 128k, dbuf,
// counted vmcnt(12). grid 512 = eb(&127) x bg(>>7) (same-eb -> same XCD).
__global__ __launch_bounds__(256, 2) void gemm_v16(
    const short* __restrict__ abf, const float* __restrict__ w,
    const float* __restrict__ bias, short* __restrict__ vout) {
  __shared__ float lwW[4][2][16 * 128];  // 64 KB
  __shared__ f32x4 red[3][64];           // 3 KB

  const int t    = threadIdx.x;
  const int lane = t & 63;
  const int wv   = t >> 6;
  const int e0   = (blockIdx.x & 127) * 16;
  const int b0   = (blockIdx.x >> 7) * 16;
  const int kq   = wv * 512;

  const int wrl = lane >> 5, wg = lane & 31;
  const int r = lane & 15, ksub = lane >> 4;
  const int q = r & 7;

  const short* abase = abf + (size_t)(b0 + r) * DM + kq + ksub * 8;
  short8 areg[2][4];
  f32x4 acc = {0.f, 0.f, 0.f, 0.f};

#define ISSUE_W(c, bsel)                                                      \
  {                                                                           \
    const int ck = kq + (c) * 128;                                            \
    float* wd = &lwW[wv][bsel][0];                                            \
    _Pragma("unroll") for (int i = 0; i < 8; ++i) {                           \
      const int row = 2 * i + wrl;                                            \
      const float* src =                                                      \
          w + (size_t)(e0 + row) * DM + ck + ((wg ^ (row & 7)) << 2);         \
      __builtin_amdgcn_global_load_lds(                                       \
          (const __attribute__((address_space(1))) void*)src,                 \
          (__attribute__((address_space(3))) void*)(wd + i * 256), 16, 0, 0); \
    }                                                                         \
  }
#define LOAD_A(c, bsel)                                                       \
  {                                                                           \
    _Pragma("unroll") for (int s = 0; s < 4; ++s) areg[bsel][s] =             \
        *reinterpret_cast<const short8*>(abase + (c) * 128 + s * 32);         \
  }

  ISSUE_W(0, 0)
  LOAD_A(0, 0)

#pragma unroll
  for (int c = 0; c < 4; ++c) {
    if (c < 3) {
      ISSUE_W(c + 1, (c + 1) & 1)
      LOAD_A(c + 1, (c + 1) & 1)
      asm volatile("s_waitcnt vmcnt(12)" ::: "memory");
    } else {
      asm volatile("s_waitcnt vmcnt(0)" ::: "memory");
    }
    __builtin_amdgcn_sched_barrier(0);

    const float* wb = &lwW[wv][c & 1][0];
#pragma unroll
    for (int s = 0; s < 4; ++s) {
      const int gl = s * 8 + ksub * 2;
      const float4 lo =
          *reinterpret_cast<const float4*>(wb + r * 128 + ((gl ^ q) << 2));
      const float4 hi = *reinterpret_cast<const float4*>(
          wb + r * 128 + (((gl + 1) ^ q) << 2));
      short8 bf;
      bf[0] = f2bf(lo.x); bf[1] = f2bf(lo.y);
      bf[2] = f2bf(lo.z); bf[3] = f2bf(lo.w);
      bf[4] = f2bf(hi.x); bf[5] = f2bf(hi.y);
      bf[6] = f2bf(hi.z); bf[7] = f2bf(hi.w);
      acc = __builtin_amdgcn_mfma_f32_16x16x32_bf16(areg[c & 1][s], bf, acc,
                                                    0, 0, 0);
    }
  }
#undef ISSUE_W
#undef LOAD_A

  if (wv != 0) red[wv - 1][lane] = acc;
  __syncthreads();
  if (wv == 0) {
#pragma unroll
    for (int i = 0; i < 3; ++i) acc += red[i][lane];
    const float be = 8.f * bias[e0 + r];
#pragma unroll
    for (int j = 0; j < 4; ++j)
      vout[(size_t)(b0 + ksub * 4 + j) * DM + e0 + r] = f2bf(acc[j] + be);
  }
}

// GEMM2: out[b][s][e] = seq[b][s][e] + (sum_k v[b][k]Wo[e][k] + 8bo[e])
// r13 structure (32e x 16b tile, full 128B epilogue lines) + seq loads
// SPREAD across the 8 chunks (1/iter): constant vmcnt(8) = chunk c+1's
// 4 W + 2 A + 1 seq plus <=1 older seq in flight; tail vmcnt(1);
// epilogue vmcnt(0). Smooths seq's 16MB across the W stream instead of
// cramming it into the last chunk (r13 serialized ~2us there).
__global__ __launch_bounds__(512, 2) void gemm_out(
    const short* __restrict__ abf, const float* __restrict__ w,
    const float* __restrict__ bias, const float* __restrict__ seq,
    float* __restrict__ out) {
  __shared__ float lwW[8][2][16 * 64];  // 64 KB
  __shared__ f32x4 red[2][3][64];       // 6 KB
  __shared__ float ptt[16][32];         // 2 KB

  const int t    = threadIdx.x;
  const int lane = t & 63;
  const int wv   = t >> 6;
  const int eh   = wv & 1;
  const int kqi  = wv >> 1;
  const int e0   = (blockIdx.x & 63) * 32;
  const int b0   = (blockIdx.x >> 6) * 16;
  const int ew   = e0 + eh * 16;
  const int kq   = kqi * 512;

  const int rl4 = lane >> 4, g = lane & 15;
  const int r = lane & 15, ksub = lane >> 4;

  const short* abase = abf + (size_t)(b0 + r) * DM + kq + ksub * 8;
  short8 areg[2][2];
  f32x4 acc = {0.f, 0.f, 0.f, 0.f};

  const int bl = t >> 5, rem = t & 31;
  const int ef4 = (rem & 7) * 4, sl = rem >> 3;
  float4 sreg[8];

#define ISSUE_W2(c, bsel)                                                     \
  {                                                                           \
    const int ck = kq + (c) * 64;                                             \
    float* wd = &lwW[wv][bsel][0];                                            \
    _Pragma("unroll") for (int i = 0; i < 4; ++i) {                           \
      const int row = 4 * i + rl4;                                            \
      const float* src =                                                      \
          w + (size_t)(ew + row) * DM + ck + ((g ^ row) << 2);                \
      __builtin_amdgcn_global_load_lds(                                       \
          (const __attribute__((address_space(1))) void*)src,                 \
          (__attribute__((address_space(3))) void*)(wd + i * 256), 16, 0, 0); \
    }                                                                         \
  }
#define LOAD_A2(c, bsel)                                                      \
  {                                                                           \
    areg[bsel][0] = *reinterpret_cast<const short8*>(abase + (c) * 64);       \
    areg[bsel][1] = *reinterpret_cast<const short8*>(abase + (c) * 64 + 32);  \
  }
#define LOAD_SEQ(i)                                                           \
  {                                                                           \
    const size_t off =                                                        \
        ((size_t)(b0 + bl) * SS + (sl + 4 * (i))) * DM + e0 + ef4;            \
    sreg[i] = *reinterpret_cast<const float4*>(seq + off);                    \
  }

  ISSUE_W2(0, 0)
  LOAD_A2(0, 0)
  LOAD_SEQ(0)

#pragma unroll
  for (int c = 0; c < 8; ++c) {
    if (c < 7) {
      ISSUE_W2(c + 1, (c + 1) & 1)
      LOAD_A2(c + 1, (c + 1) & 1)
      LOAD_SEQ(c + 1)
      asm volatile("s_waitcnt vmcnt(8)" ::: "memory");
    } else {
      asm volatile("s_waitcnt vmcnt(1)" ::: "memory");
    }
    __builtin_amdgcn_sched_barrier(0);

    const float* wb = &lwW[wv][c & 1][0];
#pragma unroll
    for (int s = 0; s < 2; ++s) {
      const int gl = s * 8 + ksub * 2;
      const float4 lo =
          *reinterpret_cast<const float4*>(wb + r * 64 + ((gl ^ r) << 2));
      const float4 hi = *reinterpret_cast<const float4*>(
          wb + r * 64 + (((gl + 1) ^ r) << 2));
      short8 bf;
      bf[0] = f2bf(lo.x); bf[1] = f2bf(lo.y);
      bf[2] = f2bf(lo.z); bf[3] = f2bf(lo.w);
      bf[4] = f2bf(hi.x); bf[5] = f2bf(hi.y);
      bf[6] = f2bf(hi.z); bf[7] = f2bf(hi.w);
      acc = __builtin_amdgcn_mfma_f32_16x16x32_bf16(areg[c & 1][s], bf, acc,
                                                    0, 0, 0);
    }
  }
#undef ISSUE_W2
#undef LOAD_A2
#undef LOAD_SEQ

  if (kqi != 0) red[eh][kqi - 1][lane] = acc;
  __syncthreads();
  if (kqi == 0) {
#pragma unroll
    for (int i = 0; i < 3; ++i) acc += red[eh][i][lane];
    const float be = 8.f * bias[ew + r];
#pragma unroll
    for (int j = 0; j < 4; ++j) ptt[ksub * 4 + j][eh * 16 + r] = acc[j] + be;
  }
  __syncthreads();

  const float4 pv = *reinterpret_cast<const float4*>(&ptt[bl][ef4]);
  asm volatile("s_waitcnt vmcnt(0)" ::: "memory");
#pragma unroll
  for (int i = 0; i < 8; ++i) {
    const size_t off = ((size_t)(b0 + bl) * SS + (sl + 4 * i)) * DM + e0 + ef4;
    *reinterpret_cast<float4*>(out + off) =
        make_float4(sreg[i].x + pv.x, sreg[i].y + pv.y, sreg[i].z + pv.z,
                    sreg[i].w + pv.w);
  }
}

extern "C" void kernel_launch(void* const* d_in, const int* in_sizes, int n_in,
                              void* d_out, int out_size, void* d_ws,
                              size_t ws_size, hipStream_t stream) {
  const float* seq      = (const float*)d_in[0];
  const float* controls = (const float*)d_in[1];
  // d_in[2..5] = Wq, bq, Wk, bk — mathematically unused (softmax over size-1 axis == 1)
  const float* Wv = (const float*)d_in[6];
  const float* bv = (const float*)d_in[7];
  const float* Wo = (const float*)d_in[8];
  const float* bo = (const float*)d_in[9];
  float* out = (float*)d_out;

  char* ws = (char*)d_ws;
  short* u16 = (short*)(ws);                   // 256 KB bf16 [64][2048]
  short* v16 = (short*)(ws + (512ull << 10));  // 256 KB bf16 [64][2048]

  k1_sum_bf16<<<256, 128, 0, stream>>>(controls, u16);
  gemm_v16<<<512, 256, 0, stream>>>(u16, Wv, bv, v16);
  gemm_out<<<256, 512, 0, stream>>>(v16, Wo, bo, seq, out);
}